// Round 2
// baseline (1264.035 us; speedup 1.0000x reference)
//
#include <hip/hip_runtime.h>

// SparseAutoencoder forward, MI355X.
//  - bf16x3 split GEMM (err ~2e-7) produces APPROX acts -> candidate nomination only.
//  - topk_cand: binary-search approx 32nd value, collect candidates (act' >= T-1e-4),
//    zero the latent row.
//  - refine_topk: fp64-exact cos/act for <=64 candidates per row (from raw fp32 inputs),
//    exact top-32 with index-ordered ties -> writes latent + topv/topi. This matches a
//    float64 numpy reference's selection exactly (fixes Round-1 rank-swap failures).
//  - recon: transpose decoder_w -> dwT, 32-term gather FMA + bias.
// ws: A' @0 (25165824 B), B' @25165824 (100663296 B);
//     dwT @0 (67108864 B, reuses A'/B' post-GEMM);
//     topv @125829120, topi @+512K, cand_idx @126877696 (1 MB), cand_cnt @127926272.

#define DEV static __device__ __forceinline__

constexpr int Bm_ = 4096;
constexpr int Dd_ = 1024;
constexpr int Hh_ = 16384;
constexpr int K3_ = 3072;
constexpr int TOPK = 32;
constexpr int CMAX = 64;

typedef __bf16 bf16x8 __attribute__((ext_vector_type(8)));
typedef float f32x4 __attribute__((ext_vector_type(4)));

DEV unsigned short f2bf_rne(float f) {
    unsigned u = __float_as_uint(f);
    unsigned r = u + 0x7FFFu + ((u >> 16) & 1u);
    return (unsigned short)(r >> 16);
}
DEV float bf2f(unsigned short h) { return __uint_as_float(((unsigned)h) << 16); }

// ---------------- prep: row L2-normalize + bf16 hi/lo split + K-pack ----------------
__global__ __launch_bounds__(256) void prep_split(const float* __restrict__ src,
                                                  unsigned short* __restrict__ dst,
                                                  int dup_off, int lo_off) {
    int row = blockIdx.x, t = threadIdx.x;
    float4 v = reinterpret_cast<const float4*>(src + (size_t)row * Dd_)[t];
    float ss = v.x * v.x + v.y * v.y + v.z * v.z + v.w * v.w;
    for (int off = 1; off < 64; off <<= 1) ss += __shfl_xor(ss, off);
    __shared__ float red[4];
    __shared__ float s_rn;
    if ((t & 63) == 0) red[t >> 6] = ss;
    __syncthreads();
    if (t == 0) s_rn = 1.0f / fmaxf(sqrtf(red[0] + red[1] + red[2] + red[3]), 1e-12f);
    __syncthreads();
    float rn = s_rn;
    float vv[4] = {v.x, v.y, v.z, v.w};
    unsigned short h[4], l[4];
#pragma unroll
    for (int j = 0; j < 4; j++) {
        float xn = vv[j] * rn;
        unsigned short hb = f2bf_rne(xn);
        h[j] = hb;
        l[j] = f2bf_rne(xn - bf2f(hb));
    }
    ushort4 hv = make_ushort4(h[0], h[1], h[2], h[3]);
    ushort4 lv = make_ushort4(l[0], l[1], l[2], l[3]);
    unsigned short* bp = dst + (size_t)row * K3_ + t * 4;
    *reinterpret_cast<ushort4*>(bp) = hv;
    *reinterpret_cast<ushort4*>(bp + dup_off) = hv;
    *reinterpret_cast<ushort4*>(bp + lo_off) = lv;
}

// ---------------- GEMM: acts' = f(A' . B'^T), 128x128 tile, m97 structure ----------------
#define BM 128
#define BN 128
#define BK 64

DEV void gload_lds16(const void* g, void* l) {
    __builtin_amdgcn_global_load_lds(
        (const __attribute__((address_space(1))) void*)g,
        (__attribute__((address_space(3))) void*)l, 16, 0, 0);
}

__global__ __launch_bounds__(256) void gemm_acts(const unsigned short* __restrict__ A,
                                                 const unsigned short* __restrict__ Bp,
                                                 float* __restrict__ acts) {
    __shared__ alignas(16) unsigned short Asl[BM * BK];
    __shared__ alignas(16) unsigned short Bsl[BN * BK];
    int t = threadIdx.x;
    int lane = t & 63, w = t >> 6;
    int wm = w >> 1, wn = w & 1;
    int mBase = blockIdx.y * BM, nBase = blockIdx.x * BN;

    f32x4 acc[4][4] = {};

    const int srow = t >> 3;
    const int scol = (t & 7) * 8;

    for (int kt = 0; kt < K3_ / BK; ++kt) {
        __syncthreads();
        const unsigned short* ag = A + (size_t)(mBase + srow) * K3_ + kt * BK + scol;
        const unsigned short* bg = Bp + (size_t)(nBase + srow) * K3_ + kt * BK + scol;
#pragma unroll
        for (int i = 0; i < 4; i++) {
            gload_lds16(ag + (size_t)i * 32 * K3_, &Asl[i * 2048 + t * 8]);
            gload_lds16(bg + (size_t)i * 32 * K3_, &Bsl[i * 2048 + t * 8]);
        }
        __syncthreads();
#pragma unroll
        for (int ks = 0; ks < 2; ++ks) {
            bf16x8 af[4], bf[4];
            int co = ks * 32 + (lane >> 4) * 8;
            int ar = wm * 64 + (lane & 15);
            int br = wn * 64 + (lane & 15);
#pragma unroll
            for (int m = 0; m < 4; m++)
                af[m] = *reinterpret_cast<const bf16x8*>(&Asl[(ar + m * 16) * BK + co]);
#pragma unroll
            for (int n = 0; n < 4; n++)
                bf[n] = *reinterpret_cast<const bf16x8*>(&Bsl[(br + n * 16) * BK + co]);
#pragma unroll
            for (int m = 0; m < 4; m++)
#pragma unroll
                for (int n = 0; n < 4; n++)
                    acc[m][n] = __builtin_amdgcn_mfma_f32_16x16x32_bf16(af[m], bf[n], acc[m][n], 0, 0, 0);
        }
    }

    int col0 = nBase + wn * 64 + (lane & 15);
    int row0 = mBase + wm * 64 + (lane >> 4) * 4;
#pragma unroll
    for (int m = 0; m < 4; m++)
#pragma unroll
        for (int n = 0; n < 4; n++)
#pragma unroll
            for (int j = 0; j < 4; j++) {
                float c = acc[m][n][j];
                c = fminf(fmaxf(c, -1.0f), 1.0f);
                float a2 = 2.0f - sqrtf(fmaxf(2.0f - 2.0f * c, 0.0f));
                acts[(size_t)(row0 + m * 16 + j) * Hh_ + (col0 + n * 16)] = a2;
            }
}

// ---------------- topk_cand: approx 32nd value, collect candidates, zero row ----------------
__global__ __launch_bounds__(256) void topk_cand(float* __restrict__ latent,
                                                 int* __restrict__ cand_idx,
                                                 int* __restrict__ cand_cnt) {
    int b = blockIdx.x, t = threadIdx.x;
    float* rowp = latent + (size_t)b * Hh_;
    unsigned u[64];
#pragma unroll
    for (int j = 0; j < 64; j++) u[j] = __float_as_uint(rowp[j * 256 + t]);

    __shared__ int red[4];
    __shared__ unsigned s_cnt;

    // acts in [0,2] -> nonneg floats -> uint order == float order
    unsigned lo = 0u, hi = 0x40000001u;
    for (int it = 0; it < 31; ++it) {
        unsigned mid = lo + ((hi - lo) >> 1);
        int c = 0;
#pragma unroll
        for (int j = 0; j < 64; j++) c += (u[j] >= mid) ? 1 : 0;
        for (int off = 1; off < 64; off <<= 1) c += __shfl_xor(c, off);
        if ((t & 63) == 0) red[t >> 6] = c;
        __syncthreads();
        c = red[0] + red[1] + red[2] + red[3];
        __syncthreads();
        if (c >= TOPK) lo = mid;
        else           hi = mid;
    }
    float Tf = __uint_as_float(lo);                       // approx 32nd-largest act
    unsigned cthr = __float_as_uint(fmaxf(Tf - 1e-4f, 0.0f));
    if (t == 0) s_cnt = 0;
    __syncthreads();
#pragma unroll
    for (int j = 0; j < 64; j++) {
        int i = j * 256 + t;
        if (u[j] >= cthr) {
            unsigned slot = atomicAdd(&s_cnt, 1u);
            if (slot < CMAX) cand_idx[b * CMAX + slot] = i;
        }
        rowp[i] = 0.0f;
    }
    __syncthreads();
    if (t == 0) cand_cnt[b] = (int)min(s_cnt, (unsigned)CMAX);
}

// ---------------- refine: fp64-exact cos/act for candidates, exact top-32 ----------------
__global__ __launch_bounds__(256) void refine_topk(const float* __restrict__ x,
                                                   const float* __restrict__ enc,
                                                   const int* __restrict__ cand_idx,
                                                   const int* __restrict__ cand_cnt,
                                                   float* __restrict__ latent,
                                                   float* __restrict__ topv,
                                                   int* __restrict__ topi) {
    int b = blockIdx.x, t = threadIdx.x;
    __shared__ float sx[Dd_];
    __shared__ double s_red[4];
    __shared__ double s_nx2;
    __shared__ double cvals[CMAX];
    __shared__ int cidx[CMAX];

    float4 xv = reinterpret_cast<const float4*>(x + (size_t)b * Dd_)[t];
    reinterpret_cast<float4*>(sx)[t] = xv;
    double ss = (double)xv.x * xv.x + (double)xv.y * xv.y +
                (double)xv.z * xv.z + (double)xv.w * xv.w;
    for (int off = 1; off < 64; off <<= 1) ss += __shfl_xor(ss, off);
    if ((t & 63) == 0) s_red[t >> 6] = ss;
    __syncthreads();
    if (t == 0) s_nx2 = s_red[0] + s_red[1] + s_red[2] + s_red[3];
    __syncthreads();
    double nx = sqrt(s_nx2);
    nx = fmax(nx, 1e-12);

    int C = cand_cnt[b];
    int wv = t >> 6, lane = t & 63;
    for (int c = wv; c < C; c += 4) {
        int j = cand_idx[b * CMAX + c];
        const float* wr = enc + (size_t)j * Dd_;
        double xw = 0.0, w2 = 0.0;
#pragma unroll
        for (int q = 0; q < 4; q++) {
            float4 wvv = reinterpret_cast<const float4*>(wr)[lane * 4 + q];
            float4 xs = reinterpret_cast<const float4*>(sx)[lane * 4 + q];
            xw += (double)xs.x * wvv.x + (double)xs.y * wvv.y +
                  (double)xs.z * wvv.z + (double)xs.w * wvv.w;
            w2 += (double)wvv.x * wvv.x + (double)wvv.y * wvv.y +
                  (double)wvv.z * wvv.z + (double)wvv.w * wvv.w;
        }
        for (int off = 1; off < 64; off <<= 1) {
            xw += __shfl_xor(xw, off);
            w2 += __shfl_xor(w2, off);
        }
        if (lane == 0) {
            double nw = fmax(sqrt(w2), 1e-12);
            double cs = xw / (nx * nw);
            cs = fmin(fmax(cs, -1.0), 1.0);
            double act = 2.0 - sqrt(fmax(2.0 - 2.0 * cs, 0.0));
            cvals[c] = act;
            cidx[c] = j;
        }
    }
    __syncthreads();
    if (t < C) {
        double v = cvals[t];
        int j = cidx[t];
        int rank = 0;
        for (int c2 = 0; c2 < C; c2++) {
            double v2 = cvals[c2];
            rank += (v2 > v) || (v2 == v && cidx[c2] < j);
        }
        if (rank < TOPK) {
            latent[(size_t)b * Hh_ + j] = (float)v;
            topv[b * TOPK + rank] = (float)v;
            topi[b * TOPK + rank] = j;
        }
    }
}

// ---------------- transpose decoder_w [D,H] -> dwT [H,D] ----------------
__global__ __launch_bounds__(256) void transpose_dw(const float* __restrict__ dw,
                                                    float* __restrict__ dwT) {
    __shared__ float tile[32][33];
    int hb = blockIdx.x * 32, db = blockIdx.y * 32;
    int tx = threadIdx.x & 31, ty = threadIdx.x >> 5;
#pragma unroll
    for (int j = 0; j < 4; j++)
        tile[ty + 8 * j][tx] = dw[(size_t)(db + ty + 8 * j) * Hh_ + hb + tx];
    __syncthreads();
#pragma unroll
    for (int j = 0; j < 4; j++)
        dwT[(size_t)(hb + ty + 8 * j) * Dd_ + db + tx] = tile[tx][ty + 8 * j];
}

// ---------------- recon: sparse gather GEMM + bias ----------------
__global__ __launch_bounds__(256) void recon_k(const float* __restrict__ topv,
                                               const int* __restrict__ topi,
                                               const float* __restrict__ dwT,
                                               const float* __restrict__ db,
                                               float* __restrict__ recon) {
    int b = blockIdx.x, t = threadIdx.x;
    __shared__ float sv[TOPK];
    __shared__ int si[TOPK];
    if (t < TOPK) { sv[t] = topv[b * TOPK + t]; si[t] = topi[b * TOPK + t]; }
    __syncthreads();
    float4 acc = reinterpret_cast<const float4*>(db)[t];
#pragma unroll 8
    for (int k = 0; k < TOPK; k++) {
        float v = sv[k];
        float4 wv = reinterpret_cast<const float4*>(dwT + (size_t)si[k] * Dd_)[t];
        acc.x += v * wv.x; acc.y += v * wv.y; acc.z += v * wv.z; acc.w += v * wv.w;
    }
    reinterpret_cast<float4*>(recon + (size_t)b * Dd_)[t] = acc;
}

extern "C" void kernel_launch(void* const* d_in, const int* in_sizes, int n_in,
                              void* d_out, int out_size, void* d_ws, size_t ws_size,
                              hipStream_t stream) {
    const float* x   = (const float*)d_in[0];
    const float* enc = (const float*)d_in[1];
    const float* dw  = (const float*)d_in[2];
    const float* db  = (const float*)d_in[3];

    float* recon  = (float*)d_out;
    float* latent = (float*)d_out + (size_t)Bm_ * Dd_;

    char* ws = (char*)d_ws;
    unsigned short* Ap = (unsigned short*)ws;
    unsigned short* Bp = (unsigned short*)(ws + 25165824);
    float* dwT   = (float*)ws;                       // reuses A'/B' post-GEMM
    float* topv  = (float*)(ws + 125829120);
    int*   topi  = (int*)(ws + 125829120 + 524288);
    int*   cidx  = (int*)(ws + 126877696);
    int*   ccnt  = (int*)(ws + 127926272);

    prep_split<<<Bm_, 256, 0, stream>>>(x, Ap, 1024, 2048);
    prep_split<<<Hh_, 256, 0, stream>>>(enc, Bp, 2048, 1024);
    gemm_acts<<<dim3(Hh_ / BN, Bm_ / BM), 256, 0, stream>>>(Ap, Bp, latent);
    transpose_dw<<<dim3(Hh_ / 32, Dd_ / 32), 256, 0, stream>>>(dw, dwT);
    topk_cand<<<Bm_, 256, 0, stream>>>(latent, cidx, ccnt);
    refine_topk<<<Bm_, 256, 0, stream>>>(x, enc, cidx, ccnt, latent, topv, topi);
    recon_k<<<Bm_, 256, 0, stream>>>(topv, topi, dwT, db, recon);
}

// Round 3
// 1232.948 us; speedup vs baseline: 1.0252x; 1.0252x over previous
//
#include <hip/hip_runtime.h>

// SparseAutoencoder forward, MI355X.
//  - bf16x3 split GEMM (err ~2e-7) -> candidate nomination; 256^2 8-wave 4-phase
//    schedule w/ counted vmcnt(8), LDS XOR-swizzle (both-sides), setprio, XCD swizzle.
//  - topk_cand: early-exit bisection threshold, collect candidates (>= T-1e-4), zero row.
//  - refine_topk: fp64-exact act for <=64 candidates/row, exact top-32 w/ index ties.
//  - recon: transpose decoder_w -> dwT, 32-term gather FMA + bias.
// ws: A' @0 (25165824 B), B' @25165824 (100663296 B);
//     dwT @0 (67108864 B, reuses A'/B' post-GEMM);
//     topv @125829120, topi @+512K, cand_idx @126877696, cand_cnt @127926272.

#define DEV static __device__ __forceinline__

constexpr int Bm_ = 4096;
constexpr int Dd_ = 1024;
constexpr int Hh_ = 16384;
constexpr int K3_ = 3072;
constexpr int TOPK = 32;
constexpr int CMAX = 64;

typedef __bf16 bf16x8 __attribute__((ext_vector_type(8)));
typedef float f32x4 __attribute__((ext_vector_type(4)));

DEV unsigned short f2bf_rne(float f) {
    unsigned u = __float_as_uint(f);
    unsigned r = u + 0x7FFFu + ((u >> 16) & 1u);
    return (unsigned short)(r >> 16);
}
DEV float bf2f(unsigned short h) { return __uint_as_float(((unsigned)h) << 16); }

// ---------------- prep: row L2-normalize + bf16 hi/lo split + K-pack ----------------
__global__ __launch_bounds__(256) void prep_split(const float* __restrict__ src,
                                                  unsigned short* __restrict__ dst,
                                                  int dup_off, int lo_off) {
    int row = blockIdx.x, t = threadIdx.x;
    float4 v = reinterpret_cast<const float4*>(src + (size_t)row * Dd_)[t];
    float ss = v.x * v.x + v.y * v.y + v.z * v.z + v.w * v.w;
    for (int off = 1; off < 64; off <<= 1) ss += __shfl_xor(ss, off);
    __shared__ float red[4];
    __shared__ float s_rn;
    if ((t & 63) == 0) red[t >> 6] = ss;
    __syncthreads();
    if (t == 0) s_rn = 1.0f / fmaxf(sqrtf(red[0] + red[1] + red[2] + red[3]), 1e-12f);
    __syncthreads();
    float rn = s_rn;
    float vv[4] = {v.x, v.y, v.z, v.w};
    unsigned short h[4], l[4];
#pragma unroll
    for (int j = 0; j < 4; j++) {
        float xn = vv[j] * rn;
        unsigned short hb = f2bf_rne(xn);
        h[j] = hb;
        l[j] = f2bf_rne(xn - bf2f(hb));
    }
    ushort4 hv = make_ushort4(h[0], h[1], h[2], h[3]);
    ushort4 lv = make_ushort4(l[0], l[1], l[2], l[3]);
    unsigned short* bp = dst + (size_t)row * K3_ + t * 4;
    *reinterpret_cast<ushort4*>(bp) = hv;
    *reinterpret_cast<ushort4*>(bp + dup_off) = hv;
    *reinterpret_cast<ushort4*>(bp + lo_off) = lv;
}

// ---------------- GEMM: 256x256 tile, BK=64, 512 thr, dbuf, swizzled, 4-phase ----------------
#define GBM 256
#define GBN 256
#define GBK 64
#define NT (K3_ / GBK)   // 48

DEV void gload_lds16(const void* g, void* l) {
    __builtin_amdgcn_global_load_lds(
        (const __attribute__((address_space(1))) void*)g,
        (__attribute__((address_space(3))) void*)l, 16, 0, 0);
}

// stage tile kt (8 x global_load_lds, 16B each); dest linear, SOURCE pre-swizzled (rule 21)
#define STAGE(buf, kt) do {                                                     \
    int koff_ = (kt) * GBK;                                                     \
    _Pragma("unroll") for (int i_ = 0; i_ < 4; i_++) {                          \
        gload_lds16(agp[i_] + koff_, &As[buf][lofs[i_]]);                       \
        gload_lds16(bgp[i_] + koff_, &Bs[buf][lofs[i_]]);                       \
    }                                                                           \
} while (0)

// one phase: (mh,nh) quadrant x K=64 -> 16 MFMA; swizzled ds_read_b128
#define PHASE(cur, mh, nh) do {                                                 \
    if ((nh) == 0) {                                                            \
        _Pragma("unroll") for (int mm = 0; mm < 4; mm++)                        \
        _Pragma("unroll") for (int ks = 0; ks < 2; ks++)                        \
            af[mm][ks] = *reinterpret_cast<const bf16x8*>(                      \
                &As[cur][(unsigned)((wm * 128 + (mh) * 64 + mm * 16 + l15) * 64 \
                                    + (((ks * 4) + g4) ^ l7) * 8)]);            \
    }                                                                           \
    _Pragma("unroll") for (int nn = 0; nn < 2; nn++)                            \
    _Pragma("unroll") for (int ks = 0; ks < 2; ks++)                            \
        bf[nn][ks] = *reinterpret_cast<const bf16x8*>(                          \
            &Bs[cur][(unsigned)((wn * 64 + (nh) * 32 + nn * 16 + l15) * 64      \
                                + (((ks * 4) + g4) ^ l7) * 8)]);                \
    asm volatile("s_waitcnt lgkmcnt(0)" ::: "memory");                          \
    __builtin_amdgcn_sched_barrier(0);                                          \
    __builtin_amdgcn_s_setprio(1);                                              \
    _Pragma("unroll") for (int mm = 0; mm < 4; mm++)                            \
    _Pragma("unroll") for (int nn = 0; nn < 2; nn++)                            \
    _Pragma("unroll") for (int ks = 0; ks < 2; ks++)                            \
        acc[(mh) * 4 + mm][(nh) * 2 + nn] = __builtin_amdgcn_mfma_f32_16x16x32_bf16( \
            af[mm][ks], bf[nn][ks], acc[(mh) * 4 + mm][(nh) * 2 + nn], 0, 0, 0); \
    __builtin_amdgcn_s_setprio(0);                                              \
    __builtin_amdgcn_s_barrier();                                               \
} while (0)

#define COMPUTE(cur) do { PHASE(cur, 0, 0); PHASE(cur, 0, 1); PHASE(cur, 1, 0); PHASE(cur, 1, 1); } while (0)

__global__ __launch_bounds__(512, 2) void gemm_acts(const unsigned short* __restrict__ A,
                                                    const unsigned short* __restrict__ Bp,
                                                    float* __restrict__ acts) {
    __shared__ unsigned short As[2][GBM * GBK];   // 2 x 32 KB
    __shared__ unsigned short Bs[2][GBN * GBK];   // 2 x 32 KB  (total 128 KiB)
    const int t = threadIdx.x;
    const int lane = t & 63, w = t >> 6;
    const int wm = w >> 2, wn = w & 3;           // 2 x 4 waves
    const int l15 = lane & 15, g4 = lane >> 4, l7 = lane & 7;

    // bijective XCD swizzle (1024 blocks, 1024 % 8 == 0)
    int bid = blockIdx.x;
    int wg = (bid & 7) * 128 + (bid >> 3);
    int mb = wg & 15, nb = wg >> 4;
    const int mBase = mb * GBM, nBase = nb * GBN;

    // staging addresses: granule p = t + i*512; r = p>>3; logical slot = (p&7) ^ (r&7)
    const unsigned short* agp[4];
    const unsigned short* bgp[4];
    unsigned lofs[4];
#pragma unroll
    for (int i = 0; i < 4; i++) {
        int p = t + i * 512;
        int r = p >> 3;
        int sl = (p & 7) ^ (r & 7);
        agp[i] = A + (size_t)(mBase + r) * K3_ + sl * 8;
        bgp[i] = Bp + (size_t)(nBase + r) * K3_ + sl * 8;
        lofs[i] = (unsigned)p * 8;
    }

    f32x4 acc[8][4] = {};
    bf16x8 af[4][2], bf[2][2];

    STAGE(0, 0);
    for (int kt = 0; kt < NT - 1; ++kt) {
        int cur = kt & 1;
        STAGE(cur ^ 1, kt + 1);                         // issue next-tile loads (stay in flight)
        asm volatile("s_waitcnt vmcnt(8)" ::: "memory"); // tile kt landed; 8 newest outstanding
        __builtin_amdgcn_sched_barrier(0);
        __builtin_amdgcn_s_barrier();
        COMPUTE(cur);
    }
    asm volatile("s_waitcnt vmcnt(0)" ::: "memory");
    __builtin_amdgcn_sched_barrier(0);
    __builtin_amdgcn_s_barrier();
    COMPUTE((NT - 1) & 1);

    // epilogue: clip + acts transform, write latent region (f32 [B,H])
    const int col0 = nBase + wn * 64 + l15;
    const int row0 = mBase + wm * 128 + g4 * 4;
#pragma unroll
    for (int m = 0; m < 8; m++)
#pragma unroll
        for (int n = 0; n < 4; n++)
#pragma unroll
            for (int j = 0; j < 4; j++) {
                float c = acc[m][n][j];
                c = fminf(fmaxf(c, -1.0f), 1.0f);
                float a2 = 2.0f - sqrtf(fmaxf(2.0f - 2.0f * c, 0.0f));
                acts[(size_t)(row0 + m * 16 + j) * Hh_ + (col0 + n * 16)] = a2;
            }
}

// ---------------- topk_cand: early-exit bisection, collect candidates, zero row ----------------
__global__ __launch_bounds__(256) void topk_cand(float* __restrict__ latent,
                                                 int* __restrict__ cand_idx,
                                                 int* __restrict__ cand_cnt) {
    int b = blockIdx.x, t = threadIdx.x;
    float* rowp = latent + (size_t)b * Hh_;
    unsigned u[64];
#pragma unroll
    for (int q = 0; q < 16; q++) {
        float4 v = reinterpret_cast<const float4*>(rowp)[q * 256 + t];
        u[q * 4 + 0] = __float_as_uint(v.x);
        u[q * 4 + 1] = __float_as_uint(v.y);
        u[q * 4 + 2] = __float_as_uint(v.z);
        u[q * 4 + 3] = __float_as_uint(v.w);
    }
    __shared__ int red[4];
    __shared__ unsigned s_cnt;

    // acts in [0,2] -> nonneg floats -> uint order == float order
    unsigned lo = 0u, hi = 0x40000001u;
    for (int it = 0; it < 31; ++it) {
        unsigned mid = lo + ((hi - lo) >> 1);
        int c = 0;
#pragma unroll
        for (int j = 0; j < 64; j++) c += (u[j] >= mid) ? 1 : 0;
        for (int off = 1; off < 64; off <<= 1) c += __shfl_xor(c, off);
        if ((t & 63) == 0) red[t >> 6] = c;
        __syncthreads();
        c = red[0] + red[1] + red[2] + red[3];
        __syncthreads();
        if (c >= TOPK) {
            lo = mid;
            if (c <= 48) break;   // count in [32,48]: good-enough threshold, window adds few
        } else {
            hi = mid;
        }
    }
    unsigned cthr = __float_as_uint(fmaxf(__uint_as_float(lo) - 1e-4f, 0.0f));
    if (t == 0) s_cnt = 0;
    __syncthreads();
    float4 z = {0.0f, 0.0f, 0.0f, 0.0f};
#pragma unroll
    for (int q = 0; q < 16; q++) {
#pragma unroll
        for (int k = 0; k < 4; k++) {
            if (u[q * 4 + k] >= cthr) {
                unsigned slot = atomicAdd(&s_cnt, 1u);
                if (slot < CMAX) cand_idx[b * CMAX + slot] = (q * 256 + t) * 4 + k;
            }
        }
        reinterpret_cast<float4*>(rowp)[q * 256 + t] = z;
    }
    __syncthreads();
    if (t == 0) cand_cnt[b] = (int)min(s_cnt, (unsigned)CMAX);
}

// ---------------- refine: fp64-exact act for candidates, exact top-32 ----------------
__global__ __launch_bounds__(256) void refine_topk(const float* __restrict__ x,
                                                   const float* __restrict__ enc,
                                                   const int* __restrict__ cand_idx,
                                                   const int* __restrict__ cand_cnt,
                                                   float* __restrict__ latent,
                                                   float* __restrict__ topv,
                                                   int* __restrict__ topi) {
    int b = blockIdx.x, t = threadIdx.x;
    __shared__ float sx[Dd_];
    __shared__ double s_red[4];
    __shared__ double s_nx2;
    __shared__ double cvals[CMAX];
    __shared__ int cidx[CMAX];

    float4 xv = reinterpret_cast<const float4*>(x + (size_t)b * Dd_)[t];
    reinterpret_cast<float4*>(sx)[t] = xv;
    double ss = (double)xv.x * xv.x + (double)xv.y * xv.y +
                (double)xv.z * xv.z + (double)xv.w * xv.w;
    for (int off = 1; off < 64; off <<= 1) ss += __shfl_xor(ss, off);
    if ((t & 63) == 0) s_red[t >> 6] = ss;
    __syncthreads();
    if (t == 0) s_nx2 = s_red[0] + s_red[1] + s_red[2] + s_red[3];
    __syncthreads();
    double nx = fmax(sqrt(s_nx2), 1e-12);

    int C = cand_cnt[b];
    int grp = t >> 5, lr = t & 31;                  // 8 groups of 32 lanes
    for (int c = grp; c < C; c += 8) {
        int j = cand_idx[b * CMAX + c];
        const float* wr = enc + (size_t)j * Dd_;
        double xw = 0.0, w2 = 0.0;
#pragma unroll
        for (int q = 0; q < 8; q++) {
            float4 wvv = reinterpret_cast<const float4*>(wr)[q * 32 + lr];
            float4 xs  = reinterpret_cast<const float4*>(sx)[q * 32 + lr];
            xw += (double)xs.x * wvv.x + (double)xs.y * wvv.y +
                  (double)xs.z * wvv.z + (double)xs.w * wvv.w;
            w2 += (double)wvv.x * wvv.x + (double)wvv.y * wvv.y +
                  (double)wvv.z * wvv.z + (double)wvv.w * wvv.w;
        }
        for (int off = 1; off < 32; off <<= 1) {
            xw += __shfl_xor(xw, off);
            w2 += __shfl_xor(w2, off);
        }
        if (lr == 0) {
            double nw = fmax(sqrt(w2), 1e-12);
            double cs = fmin(fmax(xw / (nx * nw), -1.0), 1.0);
            cvals[c] = 2.0 - sqrt(fmax(2.0 - 2.0 * cs, 0.0));
            cidx[c] = j;
        }
    }
    __syncthreads();
    if (t < C) {
        double v = cvals[t];
        int j = cidx[t];
        int rank = 0;
        for (int c2 = 0; c2 < C; c2++) {
            double v2 = cvals[c2];
            rank += (v2 > v) || (v2 == v && cidx[c2] < j);
        }
        if (rank < TOPK) {
            latent[(size_t)b * Hh_ + j] = (float)v;
            topv[b * TOPK + rank] = (float)v;
            topi[b * TOPK + rank] = j;
        }
    }
}

// ---------------- transpose decoder_w [D,H] -> dwT [H,D] ----------------
__global__ __launch_bounds__(256) void transpose_dw(const float* __restrict__ dw,
                                                    float* __restrict__ dwT) {
    __shared__ float tile[32][33];
    int hb = blockIdx.x * 32, db = blockIdx.y * 32;
    int tx = threadIdx.x & 31, ty = threadIdx.x >> 5;
#pragma unroll
    for (int j = 0; j < 4; j++)
        tile[ty + 8 * j][tx] = dw[(size_t)(db + ty + 8 * j) * Hh_ + hb + tx];
    __syncthreads();
#pragma unroll
    for (int j = 0; j < 4; j++)
        dwT[(size_t)(hb + ty + 8 * j) * Dd_ + db + tx] = tile[tx][ty + 8 * j];
}

// ---------------- recon: sparse gather GEMM + bias ----------------
__global__ __launch_bounds__(256) void recon_k(const float* __restrict__ topv,
                                               const int* __restrict__ topi,
                                               const float* __restrict__ dwT,
                                               const float* __restrict__ db,
                                               float* __restrict__ recon) {
    int b = blockIdx.x, t = threadIdx.x;
    __shared__ float sv[TOPK];
    __shared__ int si[TOPK];
    if (t < TOPK) { sv[t] = topv[b * TOPK + t]; si[t] = topi[b * TOPK + t]; }
    __syncthreads();
    float4 acc = reinterpret_cast<const float4*>(db)[t];
#pragma unroll 8
    for (int k = 0; k < TOPK; k++) {
        float v = sv[k];
        float4 wv = reinterpret_cast<const float4*>(dwT + (size_t)si[k] * Dd_)[t];
        acc.x += v * wv.x; acc.y += v * wv.y; acc.z += v * wv.z; acc.w += v * wv.w;
    }
    reinterpret_cast<float4*>(recon + (size_t)b * Dd_)[t] = acc;
}

extern "C" void kernel_launch(void* const* d_in, const int* in_sizes, int n_in,
                              void* d_out, int out_size, void* d_ws, size_t ws_size,
                              hipStream_t stream) {
    const float* x   = (const float*)d_in[0];
    const float* enc = (const float*)d_in[1];
    const float* dw  = (const float*)d_in[2];
    const float* db  = (const float*)d_in[3];

    float* recon  = (float*)d_out;
    float* latent = (float*)d_out + (size_t)Bm_ * Dd_;

    char* ws = (char*)d_ws;
    unsigned short* Ap = (unsigned short*)ws;
    unsigned short* Bp = (unsigned short*)(ws + 25165824);
    float* dwT   = (float*)ws;                       // reuses A'/B' post-GEMM
    float* topv  = (float*)(ws + 125829120);
    int*   topi  = (int*)(ws + 125829120 + 524288);
    int*   cidx  = (int*)(ws + 126877696);
    int*   ccnt  = (int*)(ws + 127926272);

    prep_split<<<Bm_, 256, 0, stream>>>(x, Ap, 1024, 2048);
    prep_split<<<Hh_, 256, 0, stream>>>(enc, Bp, 2048, 1024);
    gemm_acts<<<(Bm_ / GBM) * (Hh_ / GBN), 512, 0, stream>>>(Ap, Bp, latent);
    transpose_dw<<<dim3(Hh_ / 32, Dd_ / 32), 256, 0, stream>>>(dw, dwT);
    topk_cand<<<Bm_, 256, 0, stream>>>(latent, cidx, ccnt);
    refine_topk<<<Bm_, 256, 0, stream>>>(x, enc, cidx, ccnt, latent, topv, topi);
    recon_k<<<Bm_, 256, 0, stream>>>(topv, topi, dwT, db, recon);
}

// Round 4
// 1115.971 us; speedup vs baseline: 1.1327x; 1.1048x over previous
//
#include <hip/hip_runtime.h>

// SparseAutoencoder forward, MI355X.
//  - bf16x3 split GEMM (err ~2e-7) -> candidate nomination.
//    GEMM: 256x256, BK=64, 8 waves, 4-phase/K-tile half-tile ring:
//    stage 1 region/phase (Q0,R0,R1,Q1), vmcnt(4) at ph1-3 (never 0 in-loop),
//    2 barriers/phase, lgkmcnt(0)+sched_barrier before each 16-MFMA cluster,
//    setprio around MFMA, st-16x32-style XOR swizzle (pre-swizzled global src,
//    swizzled ds_read), bijective XCD swizzle. LDS reads minimized (24/tile/wave).
//  - topk_refine_recon (merged): bisection threshold -> candidates (LDS) -> zero row
//    -> fp64-exact act for <=64 candidates -> exact top-32 (index-ordered ties)
//    -> latent scatter -> recon = sum v_k * dwT[j_k] + bias.
// ws: A' @0 (25165824 B), B' @25165824 (100663296 B);
//     dwT @0 (67108864 B, reuses A'/B' post-GEMM).

#define DEV static __device__ __forceinline__

constexpr int Bm_ = 4096;
constexpr int Dd_ = 1024;
constexpr int Hh_ = 16384;
constexpr int K3_ = 3072;
constexpr int TOPK = 32;
constexpr int CMAX = 64;

typedef __bf16 bf16x8 __attribute__((ext_vector_type(8)));
typedef float f32x4 __attribute__((ext_vector_type(4)));

DEV unsigned short f2bf_rne(float f) {
    unsigned u = __float_as_uint(f);
    unsigned r = u + 0x7FFFu + ((u >> 16) & 1u);
    return (unsigned short)(r >> 16);
}
DEV float bf2f(unsigned short h) { return __uint_as_float(((unsigned)h) << 16); }

// ---------------- prep: row L2-normalize + bf16 hi/lo split + K-pack ----------------
__global__ __launch_bounds__(256) void prep_split(const float* __restrict__ src,
                                                  unsigned short* __restrict__ dst,
                                                  int dup_off, int lo_off) {
    int row = blockIdx.x, t = threadIdx.x;
    float4 v = reinterpret_cast<const float4*>(src + (size_t)row * Dd_)[t];
    float ss = v.x * v.x + v.y * v.y + v.z * v.z + v.w * v.w;
    for (int off = 1; off < 64; off <<= 1) ss += __shfl_xor(ss, off);
    __shared__ float red[4];
    __shared__ float s_rn;
    if ((t & 63) == 0) red[t >> 6] = ss;
    __syncthreads();
    if (t == 0) s_rn = 1.0f / fmaxf(sqrtf(red[0] + red[1] + red[2] + red[3]), 1e-12f);
    __syncthreads();
    float rn = s_rn;
    float vv[4] = {v.x, v.y, v.z, v.w};
    unsigned short h[4], l[4];
#pragma unroll
    for (int j = 0; j < 4; j++) {
        float xn = vv[j] * rn;
        unsigned short hb = f2bf_rne(xn);
        h[j] = hb;
        l[j] = f2bf_rne(xn - bf2f(hb));
    }
    ushort4 hv = make_ushort4(h[0], h[1], h[2], h[3]);
    ushort4 lv = make_ushort4(l[0], l[1], l[2], l[3]);
    unsigned short* bp = dst + (size_t)row * K3_ + t * 4;
    *reinterpret_cast<ushort4*>(bp) = hv;
    *reinterpret_cast<ushort4*>(bp + dup_off) = hv;
    *reinterpret_cast<ushort4*>(bp + lo_off) = lv;
}

// ---------------- GEMM ----------------
#define GBM 256
#define GBN 256
#define GBK 64
#define NT 48

DEV void gload_lds16(const void* g, void* l) {
    __builtin_amdgcn_global_load_lds(
        (const __attribute__((address_space(1))) void*)g,
        (__attribute__((address_space(3))) void*)l, 16, 0, 0);
}

// stage one region (2 x global_load_lds per thread); dest linear, source pre-swizzled
#define STG_A(bb, h, ko) do {                                                   \
    gload_lds16(Ab + aoff[h][0] + (ko), &As[bb][h][lofs[0]]);                   \
    gload_lds16(Ab + aoff[h][1] + (ko), &As[bb][h][lofs[1]]); } while (0)
#define STG_B(bb, h, ko) do {                                                   \
    gload_lds16(Bb + boff[h][0] + (ko), &Bs[bb][h][lofs[0]]);                   \
    gload_lds16(Bb + boff[h][1] + (ko), &Bs[bb][h][lofs[1]]); } while (0)

#define LD_AF(bb, mh) do { _Pragma("unroll") for (int mm = 0; mm < 4; mm++)     \
    _Pragma("unroll") for (int ks = 0; ks < 2; ks++)                            \
        af[mm][ks] = *reinterpret_cast<const bf16x8*>(                          \
            &As[bb][mh][(wm * 64 + mm * 16 + l15) * 64 +                        \
                        (((ks * 4) + g4) ^ l7) * 8]); } while (0)
#define LD_BF(dst, bb, nh) do { _Pragma("unroll") for (int nn = 0; nn < 2; nn++) \
    _Pragma("unroll") for (int ks = 0; ks < 2; ks++)                            \
        dst[nn][ks] = *reinterpret_cast<const bf16x8*>(                         \
            &Bs[bb][nh][(wn * 32 + nn * 16 + l15) * 64 +                        \
                        (((ks * 4) + g4) ^ l7) * 8]); } while (0)

#define MFMA16(mh, nh, BF) do {                                                 \
    __builtin_amdgcn_s_setprio(1);                                              \
    _Pragma("unroll") for (int mm = 0; mm < 4; mm++)                            \
    _Pragma("unroll") for (int nn = 0; nn < 2; nn++)                            \
    _Pragma("unroll") for (int ks = 0; ks < 2; ks++)                            \
        acc[(mh) * 4 + mm][(nh) * 2 + nn] = __builtin_amdgcn_mfma_f32_16x16x32_bf16( \
            af[mm][ks], BF[nn][ks], acc[(mh) * 4 + mm][(nh) * 2 + nn], 0, 0, 0); \
    __builtin_amdgcn_s_setprio(0); } while (0)

#define VMW4 asm volatile("s_waitcnt vmcnt(4)" ::: "memory")
#define LGKM0 do { asm volatile("s_waitcnt lgkmcnt(0)" ::: "memory");           \
                   __builtin_amdgcn_sched_barrier(0); } while (0)
#define BAR __builtin_amdgcn_s_barrier()

__global__ __launch_bounds__(512, 2) void gemm_acts(const unsigned short* __restrict__ A,
                                                    const unsigned short* __restrict__ Bp,
                                                    float* __restrict__ acts) {
    // region layout: As[buf][mh] rows lr=wm*64+r <-> global row wm*128+mh*64+r
    //                Bs[buf][nh] rows lr=wn*32+r <-> global row wn*64+nh*32+r
    __shared__ unsigned short As[2][2][128 * 64];
    __shared__ unsigned short Bs[2][2][128 * 64];
    const int t = threadIdx.x;
    const int lane = t & 63, w = t >> 6;
    const int wm = w >> 2, wn = w & 3;            // 2 x 4 waves, each 128x64 of C
    const int l15 = lane & 15, g4 = lane >> 4, l7 = lane & 7;

    // bijective XCD swizzle (1024 blocks, 1024 % 8 == 0)
    const int bid = blockIdx.x;
    const int wg = (bid & 7) * 128 + (bid >> 3);
    const int mb = wg & 15, nb = wg >> 4;
    const unsigned short* Ab = A + (size_t)(mb * GBM) * K3_;
    const unsigned short* Bb = Bp + (size_t)(nb * GBN) * K3_;

    int aoff[2][2], boff[2][2];                   // [region][load] source elem offsets
    int lofs[2];
#pragma unroll
    for (int i = 0; i < 2; i++) {
        int p = t + i * 512;                      // granule 0..1023 (16B each)
        int lr = p >> 3;                          // region-local row 0..127
        int sg = (p & 7) ^ (lr & 7);              // inverse-swizzled source col-group
        lofs[i] = p * 8;
#pragma unroll
        for (int h = 0; h < 2; h++) {
            aoff[h][i] = ((lr >> 6) * 128 + h * 64 + (lr & 63)) * K3_ + sg * 8;
            boff[h][i] = ((lr >> 5) * 64 + h * 32 + (lr & 31)) * K3_ + sg * 8;
        }
    }

    f32x4 acc[8][4] = {};
    bf16x8 af[4][2], bfA[2][2], bfB[2][2];

    // prologue: tile 0 regions in FIFO consumption order Q0, R0, R1, Q1
    STG_A(0, 0, 0);
    STG_B(0, 0, 0);
    STG_B(0, 1, 0);
    STG_A(0, 1, 0);

    for (int kt = 0; kt < NT; ++kt) {
        const int cur = kt & 1, nxt = cur ^ 1;
        const int ko = (kt < NT - 1 ? kt + 1 : kt) * GBK;  // last iter: harmless re-stage
        // phase 1 (mh0,nh0): needs Q0,R0 (oldest 4 loads) -> vmcnt(4)
        VMW4; BAR;
        LD_AF(cur, 0);
        LD_BF(bfA, cur, 0);
        STG_A(nxt, 0, ko);
        BAR; LGKM0;
        MFMA16(0, 0, bfA);
        // phase 2 (mh0,nh1): needs R1
        VMW4; BAR;
        LD_BF(bfB, cur, 1);
        STG_B(nxt, 0, ko);
        BAR; LGKM0;
        MFMA16(0, 1, bfB);
        // phase 3 (mh1,nh0): needs Q1; af storage reused for mh=1
        VMW4; BAR;
        LD_AF(cur, 1);
        STG_B(nxt, 1, ko);
        BAR; LGKM0;
        MFMA16(1, 0, bfA);
        // phase 4 (mh1,nh1): nothing new needed; no ds_reads
        BAR;
        STG_A(nxt, 1, ko);
        BAR;
        MFMA16(1, 1, bfB);
    }

    // epilogue: clip + acts transform, write latent region (f32 [B,H])
    const int col0 = nb * GBN + wn * 64 + l15;
    const int row0 = mb * GBM + wm * 128 + g4 * 4;
#pragma unroll
    for (int m = 0; m < 8; m++)
#pragma unroll
        for (int n = 0; n < 4; n++)
#pragma unroll
            for (int j = 0; j < 4; j++) {
                float c = acc[m][n][j];
                c = fminf(fmaxf(c, -1.0f), 1.0f);
                float a2 = 2.0f - sqrtf(fmaxf(2.0f - 2.0f * c, 0.0f));
                acts[(size_t)(row0 + m * 16 + j) * Hh_ + (col0 + n * 16)] = a2;
            }
}

// ---------------- merged: topk candidates -> fp64 refine -> recon ----------------
__global__ __launch_bounds__(256) void topk_refine_recon(float* __restrict__ latent,
                                                         const float* __restrict__ x,
                                                         const float* __restrict__ enc,
                                                         const float* __restrict__ dwT,
                                                         const float* __restrict__ dbias,
                                                         float* __restrict__ recon) {
    int b = blockIdx.x, t = threadIdx.x;
    float* rowp = latent + (size_t)b * Hh_;
    unsigned u[64];
#pragma unroll
    for (int q = 0; q < 16; q++) {
        float4 v = reinterpret_cast<const float4*>(rowp)[q * 256 + t];
        u[q * 4 + 0] = __float_as_uint(v.x);
        u[q * 4 + 1] = __float_as_uint(v.y);
        u[q * 4 + 2] = __float_as_uint(v.z);
        u[q * 4 + 3] = __float_as_uint(v.w);
    }
    __shared__ int red[4];
    __shared__ unsigned s_cnt;
    __shared__ int s_cidx[CMAX];
    __shared__ float sx[Dd_];
    __shared__ double s_redd[4];
    __shared__ double s_nx2;
    __shared__ double cvals[CMAX];
    __shared__ int cjd[CMAX];
    __shared__ float sv[TOPK];
    __shared__ int si[TOPK];

    // bisection on float bits (acts >= 0): approx 32nd-largest
    unsigned lo = 0u, hi = 0x40000001u;
    for (int it = 0; it < 31; ++it) {
        unsigned mid = lo + ((hi - lo) >> 1);
        int c = 0;
#pragma unroll
        for (int j = 0; j < 64; j++) c += (u[j] >= mid) ? 1 : 0;
        for (int off = 1; off < 64; off <<= 1) c += __shfl_xor(c, off);
        if ((t & 63) == 0) red[t >> 6] = c;
        __syncthreads();
        c = red[0] + red[1] + red[2] + red[3];
        __syncthreads();
        if (c >= TOPK) {
            lo = mid;
            if (c <= 48) break;       // block-uniform exit
        } else {
            hi = mid;
        }
    }
    unsigned cthr = __float_as_uint(fmaxf(__uint_as_float(lo) - 1e-4f, 0.0f));
    if (t == 0) s_cnt = 0;
    __syncthreads();
    float4 z = {0.0f, 0.0f, 0.0f, 0.0f};
#pragma unroll
    for (int q = 0; q < 16; q++) {
#pragma unroll
        for (int k = 0; k < 4; k++) {
            if (u[q * 4 + k] >= cthr) {
                unsigned slot = atomicAdd(&s_cnt, 1u);
                if (slot < CMAX) s_cidx[slot] = (q * 256 + t) * 4 + k;
            }
        }
        reinterpret_cast<float4*>(rowp)[q * 256 + t] = z;   // zero the row
    }
    // x row into LDS + fp64 norm
    float4 xv = reinterpret_cast<const float4*>(x + (size_t)b * Dd_)[t];
    reinterpret_cast<float4*>(sx)[t] = xv;
    double ss = (double)xv.x * xv.x + (double)xv.y * xv.y +
                (double)xv.z * xv.z + (double)xv.w * xv.w;
    for (int off = 1; off < 64; off <<= 1) ss += __shfl_xor(ss, off);
    if ((t & 63) == 0) s_redd[t >> 6] = ss;
    __syncthreads();
    if (t == 0) s_nx2 = s_redd[0] + s_redd[1] + s_redd[2] + s_redd[3];
    __syncthreads();
    double nx = fmax(sqrt(s_nx2), 1e-12);
    int C = (int)min(s_cnt, (unsigned)CMAX);

    // fp64-exact act per candidate (8 groups of 32 lanes)
    int grp = t >> 5, lr = t & 31;
    for (int c = grp; c < C; c += 8) {
        int j = s_cidx[c];
        const float* wr = enc + (size_t)j * Dd_;
        double xw = 0.0, w2 = 0.0;
#pragma unroll
        for (int q = 0; q < 8; q++) {
            float4 wvv = reinterpret_cast<const float4*>(wr)[q * 32 + lr];
            float4 xs  = reinterpret_cast<const float4*>(sx)[q * 32 + lr];
            xw += (double)xs.x * wvv.x + (double)xs.y * wvv.y +
                  (double)xs.z * wvv.z + (double)xs.w * wvv.w;
            w2 += (double)wvv.x * wvv.x + (double)wvv.y * wvv.y +
                  (double)wvv.z * wvv.z + (double)wvv.w * wvv.w;
        }
        for (int off = 1; off < 32; off <<= 1) {
            xw += __shfl_xor(xw, off);
            w2 += __shfl_xor(w2, off);
        }
        if (lr == 0) {
            double nw = fmax(sqrt(w2), 1e-12);
            double cs = fmin(fmax(xw / (nx * nw), -1.0), 1.0);
            cvals[c] = 2.0 - sqrt(fmax(2.0 - 2.0 * cs, 0.0));
            cjd[c] = j;
        }
    }
    __syncthreads();
    // exact top-32 with index-ordered ties; scatter latent, stash (v, j) by rank
    if (t < C) {
        double v = cvals[t];
        int j = cjd[t];
        int rank = 0;
        for (int c2 = 0; c2 < C; c2++) {
            double v2 = cvals[c2];
            rank += (v2 > v) || (v2 == v && cjd[c2] < j);
        }
        if (rank < TOPK) {
            latent[(size_t)b * Hh_ + j] = (float)v;
            sv[rank] = (float)v;
            si[rank] = j;
        }
    }
    __syncthreads();
    // recon = sum v_k * dwT[j_k][:] + bias
    float4 acc = reinterpret_cast<const float4*>(dbias)[t];
#pragma unroll 8
    for (int k = 0; k < TOPK; k++) {
        float v = sv[k];
        float4 wv = reinterpret_cast<const float4*>(dwT + (size_t)si[k] * Dd_)[t];
        acc.x += v * wv.x; acc.y += v * wv.y; acc.z += v * wv.z; acc.w += v * wv.w;
    }
    reinterpret_cast<float4*>(recon + (size_t)b * Dd_)[t] = acc;
}

// ---------------- transpose decoder_w [D,H] -> dwT [H,D] ----------------
__global__ __launch_bounds__(256) void transpose_dw(const float* __restrict__ dw,
                                                    float* __restrict__ dwT) {
    __shared__ float tile[32][33];
    int hb = blockIdx.x * 32, db = blockIdx.y * 32;
    int tx = threadIdx.x & 31, ty = threadIdx.x >> 5;
#pragma unroll
    for (int j = 0; j < 4; j++)
        tile[ty + 8 * j][tx] = dw[(size_t)(db + ty + 8 * j) * Hh_ + hb + tx];
    __syncthreads();
#pragma unroll
    for (int j = 0; j < 4; j++)
        dwT[(size_t)(hb + ty + 8 * j) * Dd_ + db + tx] = tile[tx][ty + 8 * j];
}

extern "C" void kernel_launch(void* const* d_in, const int* in_sizes, int n_in,
                              void* d_out, int out_size, void* d_ws, size_t ws_size,
                              hipStream_t stream) {
    const float* x   = (const float*)d_in[0];
    const float* enc = (const float*)d_in[1];
    const float* dw  = (const float*)d_in[2];
    const float* db  = (const float*)d_in[3];

    float* recon  = (float*)d_out;
    float* latent = (float*)d_out + (size_t)Bm_ * Dd_;

    char* ws = (char*)d_ws;
    unsigned short* Ap = (unsigned short*)ws;
    unsigned short* Bp = (unsigned short*)(ws + 25165824);
    float* dwT = (float*)ws;                      // reuses A'/B' post-GEMM

    prep_split<<<Bm_, 256, 0, stream>>>(x, Ap, 1024, 2048);
    prep_split<<<Hh_, 256, 0, stream>>>(enc, Bp, 2048, 1024);
    gemm_acts<<<(Bm_ / GBM) * (Hh_ / GBN), 512, 0, stream>>>(Ap, Bp, latent);
    transpose_dw<<<dim3(Hh_ / 32, Dd_ / 32), 256, 0, stream>>>(dw, dwT);
    topk_refine_recon<<<Bm_, 256, 0, stream>>>(latent, x, enc, dwT, db, recon);
}

// Round 6
// 947.161 us; speedup vs baseline: 1.3346x; 1.1782x over previous
//
#include <hip/hip_runtime.h>

// SparseAutoencoder forward, MI355X.
//  - bf16x3 split GEMM (err ~4e-7 rms) -> candidate nomination.
//    GEMM: 256x256, BK=64, 8 waves, ONE barrier + ONE vmcnt(0) per K-tile:
//    tile-top {vmcnt(0); barrier} (loads have full-tile lead -> wait~0), then
//    issue ds_reads ahead of MFMA clusters (compiler emits counted lgkmcnt ->
//    LDS service overlaps MFMA), stage next tile mid-compute, setprio on MFMA,
//    st-style XOR swizzle (pre-swizzled global src, swizzled ds_read),
//    bijective XCD swizzle.
//  - tail (merged): bisect exact 32nd value (exit c==32) -> candidates within
//    1e-5 window; if exactly 32 -> fast path (no fp64, no enc gather: set ==
//    true top-32 since window >> 2*gemm_err); else fp64-exact refine.
//    Then recon = sum v_k * dwT[j_k] + bias.
// ws: A' @0 (25165824 B), B' @25165824 (100663296 B);
//     dwT @0 (67108864 B, reuses A'/B' post-GEMM).

#define DEV static __device__ __forceinline__

constexpr int Bm_ = 4096;
constexpr int Dd_ = 1024;
constexpr int Hh_ = 16384;
constexpr int K3_ = 3072;
constexpr int TOPK = 32;
constexpr int CMAX = 64;

typedef __bf16 bf16x8 __attribute__((ext_vector_type(8)));
typedef float f32x4 __attribute__((ext_vector_type(4)));

DEV unsigned short f2bf_rne(float f) {
    unsigned u = __float_as_uint(f);
    unsigned r = u + 0x7FFFu + ((u >> 16) & 1u);
    return (unsigned short)(r >> 16);
}
DEV float bf2f(unsigned short h) { return __uint_as_float(((unsigned)h) << 16); }

// ---------------- prep: row L2-normalize + bf16 hi/lo split + K-pack ----------------
__global__ __launch_bounds__(256) void prep_split(const float* __restrict__ src,
                                                  unsigned short* __restrict__ dst,
                                                  int dup_off, int lo_off) {
    int row = blockIdx.x, t = threadIdx.x;
    float4 v = reinterpret_cast<const float4*>(src + (size_t)row * Dd_)[t];
    float ss = v.x * v.x + v.y * v.y + v.z * v.z + v.w * v.w;
    for (int off = 1; off < 64; off <<= 1) ss += __shfl_xor(ss, off);
    __shared__ float red[4];
    __shared__ float s_rn;
    if ((t & 63) == 0) red[t >> 6] = ss;
    __syncthreads();
    if (t == 0) s_rn = 1.0f / fmaxf(sqrtf(red[0] + red[1] + red[2] + red[3]), 1e-12f);
    __syncthreads();
    float rn = s_rn;
    float vv[4] = {v.x, v.y, v.z, v.w};
    unsigned short h[4], l[4];
#pragma unroll
    for (int j = 0; j < 4; j++) {
        float xn = vv[j] * rn;
        unsigned short hb = f2bf_rne(xn);
        h[j] = hb;
        l[j] = f2bf_rne(xn - bf2f(hb));
    }
    ushort4 hv = make_ushort4(h[0], h[1], h[2], h[3]);
    ushort4 lv = make_ushort4(l[0], l[1], l[2], l[3]);
    unsigned short* bp = dst + (size_t)row * K3_ + t * 4;
    *reinterpret_cast<ushort4*>(bp) = hv;
    *reinterpret_cast<ushort4*>(bp + dup_off) = hv;
    *reinterpret_cast<ushort4*>(bp + lo_off) = lv;
}

// ---------------- GEMM ----------------
#define GBM 256
#define GBN 256
#define GBK 64
#define NT 48

DEV void gload_lds16(const void* g, void* l) {
    __builtin_amdgcn_global_load_lds(
        (const __attribute__((address_space(1))) void*)g,
        (__attribute__((address_space(3))) void*)l, 16, 0, 0);
}

#define LD_AF(bb, mh) do { _Pragma("unroll") for (int mm = 0; mm < 4; mm++)     \
    _Pragma("unroll") for (int ks = 0; ks < 2; ks++)                            \
        af[mm][ks] = *reinterpret_cast<const bf16x8*>(                          \
            &As[bb][(wm * 128 + (mh) * 64 + mm * 16 + l15) * 64 +               \
                    (((ks * 4) + g4) ^ l7) * 8]); } while (0)
#define LD_BF(dst, bb, nh) do { _Pragma("unroll") for (int nn = 0; nn < 2; nn++) \
    _Pragma("unroll") for (int ks = 0; ks < 2; ks++)                            \
        dst[nn][ks] = *reinterpret_cast<const bf16x8*>(                         \
            &Bs[bb][(wn * 64 + (nh) * 32 + nn * 16 + l15) * 64 +                \
                    (((ks * 4) + g4) ^ l7) * 8]); } while (0)

#define MFMA16(mh, nh, BF) do {                                                 \
    __builtin_amdgcn_s_setprio(1);                                              \
    _Pragma("unroll") for (int mm = 0; mm < 4; mm++)                            \
    _Pragma("unroll") for (int nn = 0; nn < 2; nn++)                            \
    _Pragma("unroll") for (int ks = 0; ks < 2; ks++)                            \
        acc[(mh) * 4 + mm][(nh) * 2 + nn] = __builtin_amdgcn_mfma_f32_16x16x32_bf16( \
            af[mm][ks], BF[nn][ks], acc[(mh) * 4 + mm][(nh) * 2 + nn], 0, 0, 0); \
    __builtin_amdgcn_s_setprio(0); } while (0)

#define SBAR __builtin_amdgcn_sched_barrier(0)

__global__ __launch_bounds__(512, 2) void gemm_acts(const unsigned short* __restrict__ A,
                                                    const unsigned short* __restrict__ Bp,
                                                    float* __restrict__ acts) {
    __shared__ unsigned short As[2][GBM * GBK];   // 2 x 32 KB
    __shared__ unsigned short Bs[2][GBN * GBK];   // 2 x 32 KB
    const int t = threadIdx.x;
    const int lane = t & 63, w = t >> 6;
    const int wm = w >> 2, wn = w & 3;            // 2 x 4 waves, each 128x64 of C
    const int l15 = lane & 15, g4 = lane >> 4, l7 = lane & 7;

    // bijective XCD swizzle (1024 blocks, 1024 % 8 == 0)
    const int bid = blockIdx.x;
    const int wg = (bid & 7) * 128 + (bid >> 3);
    const int mb = wg & 15, nb = wg >> 4;
    const unsigned short* Ab = A + (size_t)(mb * GBM) * K3_;
    const unsigned short* Bb = Bp + (size_t)(nb * GBN) * K3_;

    // staging: 4 A + 4 B granules (16B) per thread; dest linear, src pre-swizzled
    const unsigned short* asrc[4];
    const unsigned short* bsrc[4];
    unsigned adst[4];
#pragma unroll
    for (int i = 0; i < 4; i++) {
        int p = t + i * 512;                      // 0..2047
        int r = p >> 3;                           // row 0..255
        int sg = (p & 7) ^ (r & 7);               // inverse-swizzled col-group
        asrc[i] = Ab + (size_t)r * K3_ + sg * 8;
        bsrc[i] = Bb + (size_t)r * K3_ + sg * 8;
        adst[i] = (unsigned)p * 8;
    }

    f32x4 acc[8][4] = {};
    bf16x8 af[4][2], bfA[2][2], bfB[2][2];

    // prologue: stage tile 0 into buf 0
#pragma unroll
    for (int i = 0; i < 4; i++) gload_lds16(asrc[i], &As[0][adst[i]]);
#pragma unroll
    for (int i = 0; i < 4; i++) gload_lds16(bsrc[i], &Bs[0][adst[i]]);

    for (int kt = 0; kt < NT; ++kt) {
        const int cur = kt & 1, nxt = cur ^ 1;
        const int ko = (kt < NT - 1 ? (kt + 1) : kt) * GBK;   // last: harmless re-stage
        asm volatile("s_waitcnt vmcnt(0)" ::: "memory");      // tile kt landed (full-tile lead)
        SBAR;
        __builtin_amdgcn_s_barrier();
        // issue reads for quadrants (0,0),(0,1) + both B halves; stage next A
        LD_AF(cur, 0);
        LD_BF(bfA, cur, 0);
        LD_BF(bfB, cur, 1);
#pragma unroll
        for (int i = 0; i < 4; i++) gload_lds16(asrc[i] + ko, &As[nxt][adst[i]]);
        SBAR;   // pin: reads+stages issued before MFMA; counted lgkm overlaps LDS w/ MFMA
        MFMA16(0, 0, bfA);
        MFMA16(0, 1, bfB);
        SBAR;
        LD_AF(cur, 1);                            // af regs reused for mh=1
#pragma unroll
        for (int i = 0; i < 4; i++) gload_lds16(bsrc[i] + ko, &Bs[nxt][adst[i]]);
        SBAR;
        MFMA16(1, 0, bfA);
        MFMA16(1, 1, bfB);
    }

    // epilogue: clip + acts transform, write latent region (f32 [B,H])
    const int col0 = nb * GBN + wn * 64 + l15;
    const int row0 = mb * GBM + wm * 128 + g4 * 4;
#pragma unroll
    for (int m = 0; m < 8; m++)
#pragma unroll
        for (int n = 0; n < 4; n++)
#pragma unroll
            for (int j = 0; j < 4; j++) {
                float c = acc[m][n][j];
                c = fminf(fmaxf(c, -1.0f), 1.0f);
                float a2 = 2.0f - sqrtf(fmaxf(2.0f - 2.0f * c, 0.0f));
                acts[(size_t)(row0 + m * 16 + j) * Hh_ + (col0 + n * 16)] = a2;
            }
}

// ---------------- merged tail: topk candidates -> (fast | fp64 refine) -> recon ----------------
__global__ __launch_bounds__(256) void topk_refine_recon(float* __restrict__ latent,
                                                         const float* __restrict__ x,
                                                         const float* __restrict__ enc,
                                                         const float* __restrict__ dwT,
                                                         const float* __restrict__ dbias,
                                                         float* __restrict__ recon) {
    int b = blockIdx.x, t = threadIdx.x;
    float* rowp = latent + (size_t)b * Hh_;
    unsigned u[64];
#pragma unroll
    for (int q = 0; q < 16; q++) {
        float4 v = reinterpret_cast<const float4*>(rowp)[q * 256 + t];
        u[q * 4 + 0] = __float_as_uint(v.x);
        u[q * 4 + 1] = __float_as_uint(v.y);
        u[q * 4 + 2] = __float_as_uint(v.z);
        u[q * 4 + 3] = __float_as_uint(v.w);
    }
    __shared__ int red[4];
    __shared__ unsigned s_cnt;
    __shared__ int s_cidx[CMAX];
    __shared__ float s_cval[CMAX];
    __shared__ float sx[Dd_];
    __shared__ double s_redd[4];
    __shared__ double s_nx2;
    __shared__ double cvals[CMAX];
    __shared__ int cjd[CMAX];
    __shared__ float sv[TOPK];
    __shared__ int si[TOPK];

    // bisection on float bits (acts >= 0): exact 32nd-largest (exit when count==32)
    unsigned lo = 0u, hi = 0x40000001u;
    for (int it = 0; it < 31; ++it) {
        unsigned mid = lo + ((hi - lo) >> 1);
        int c = 0;
#pragma unroll
        for (int j = 0; j < 64; j++) c += (u[j] >= mid) ? 1 : 0;
        for (int off = 1; off < 64; off <<= 1) c += __shfl_xor(c, off);
        if ((t & 63) == 0) red[t >> 6] = c;
        __syncthreads();
        c = red[0] + red[1] + red[2] + red[3];
        __syncthreads();
        if (c >= TOPK) {
            lo = mid;
            if (c == TOPK) break;     // block-uniform exit: exact threshold found
        } else {
            hi = mid;
        }
    }
    // window 1e-5 >> 2*gemm_err (~1e-6 at 12 sigma): true top-32 subset of candidates
    unsigned cthr = __float_as_uint(fmaxf(__uint_as_float(lo) - 1e-5f, 0.0f));
    if (t == 0) s_cnt = 0;
    __syncthreads();
    float4 z = {0.0f, 0.0f, 0.0f, 0.0f};
#pragma unroll
    for (int q = 0; q < 16; q++) {
#pragma unroll
        for (int k = 0; k < 4; k++) {
            if (u[q * 4 + k] >= cthr) {
                unsigned slot = atomicAdd(&s_cnt, 1u);
                if (slot < CMAX) {
                    s_cidx[slot] = (q * 256 + t) * 4 + k;
                    s_cval[slot] = __uint_as_float(u[q * 4 + k]);
                }
            }
        }
        reinterpret_cast<float4*>(rowp)[q * 256 + t] = z;   // zero the row
    }
    __syncthreads();
    int C = (int)min(s_cnt, (unsigned)CMAX);

    if (C == TOPK) {
        // fast path: candidate set IS the true top-32; approx values within 4e-7
        if (t < TOPK) {
            sv[t] = s_cval[t];
            si[t] = s_cidx[t];
            latent[(size_t)b * Hh_ + s_cidx[t]] = s_cval[t];
        }
    } else {
        // rare path: fp64-exact acts for all candidates, exact top-32 w/ index ties
        float4 xv = reinterpret_cast<const float4*>(x + (size_t)b * Dd_)[t];
        reinterpret_cast<float4*>(sx)[t] = xv;
        double ss = (double)xv.x * xv.x + (double)xv.y * xv.y +
                    (double)xv.z * xv.z + (double)xv.w * xv.w;
        for (int off = 1; off < 64; off <<= 1) ss += __shfl_xor(ss, off);
        if ((t & 63) == 0) s_redd[t >> 6] = ss;
        __syncthreads();
        if (t == 0) s_nx2 = s_redd[0] + s_redd[1] + s_redd[2] + s_redd[3];
        __syncthreads();
        double nx = fmax(sqrt(s_nx2), 1e-12);

        int grp = t >> 5, lr = t & 31;
        for (int c = grp; c < C; c += 8) {
            int j = s_cidx[c];
            const float* wr = enc + (size_t)j * Dd_;
            double xw = 0.0, w2 = 0.0;
#pragma unroll
            for (int q = 0; q < 8; q++) {
                float4 wvv = reinterpret_cast<const float4*>(wr)[q * 32 + lr];
                float4 xs  = reinterpret_cast<const float4*>(sx)[q * 32 + lr];
                xw += (double)xs.x * wvv.x + (double)xs.y * wvv.y +
                      (double)xs.z * wvv.z + (double)xs.w * wvv.w;
                w2 += (double)wvv.x * wvv.x + (double)wvv.y * wvv.y +
                      (double)wvv.z * wvv.z + (double)wvv.w * wvv.w;
            }
            for (int off = 1; off < 32; off <<= 1) {
                xw += __shfl_xor(xw, off);
                w2 += __shfl_xor(w2, off);
            }
            if (lr == 0) {
                double nw = fmax(sqrt(w2), 1e-12);
                double cs = fmin(fmax(xw / (nx * nw), -1.0), 1.0);
                cvals[c] = 2.0 - sqrt(fmax(2.0 - 2.0 * cs, 0.0));
                cjd[c] = j;
            }
        }
        __syncthreads();
        if (t < C) {
            double v = cvals[t];
            int j = cjd[t];
            int rank = 0;
            for (int c2 = 0; c2 < C; c2++) {
                double v2 = cvals[c2];
                rank += (v2 > v) || (v2 == v && cjd[c2] < j);
            }
            if (rank < TOPK) {
                latent[(size_t)b * Hh_ + j] = (float)v;
                sv[rank] = (float)v;
                si[rank] = j;
            }
        }
    }
    __syncthreads();
    // recon = sum v_k * dwT[j_k][:] + bias
    float4 acc = reinterpret_cast<const float4*>(dbias)[t];
#pragma unroll 8
    for (int k = 0; k < TOPK; k++) {
        float v = sv[k];
        float4 wv = reinterpret_cast<const float4*>(dwT + (size_t)si[k] * Dd_)[t];
        acc.x += v * wv.x; acc.y += v * wv.y; acc.z += v * wv.z; acc.w += v * wv.w;
    }
    reinterpret_cast<float4*>(recon + (size_t)b * Dd_)[t] = acc;
}

// ---------------- transpose decoder_w [D,H] -> dwT [H,D] ----------------
__global__ __launch_bounds__(256) void transpose_dw(const float* __restrict__ dw,
                                                    float* __restrict__ dwT) {
    __shared__ float tile[32][33];
    int hb = blockIdx.x * 32, db = blockIdx.y * 32;
    int tx = threadIdx.x & 31, ty = threadIdx.x >> 5;
#pragma unroll
    for (int j = 0; j < 4; j++)
        tile[ty + 8 * j][tx] = dw[(size_t)(db + ty + 8 * j) * Hh_ + hb + tx];
    __syncthreads();
#pragma unroll
    for (int j = 0; j < 4; j++)
        dwT[(size_t)(hb + ty + 8 * j) * Dd_ + db + tx] = tile[tx][ty + 8 * j];
}

extern "C" void kernel_launch(void* const* d_in, const int* in_sizes, int n_in,
                              void* d_out, int out_size, void* d_ws, size_t ws_size,
                              hipStream_t stream) {
    const float* x   = (const float*)d_in[0];
    const float* enc = (const float*)d_in[1];
    const float* dw  = (const float*)d_in[2];
    const float* db  = (const float*)d_in[3];

    float* recon  = (float*)d_out;
    float* latent = (float*)d_out + (size_t)Bm_ * Dd_;

    char* ws = (char*)d_ws;
    unsigned short* Ap = (unsigned short*)ws;
    unsigned short* Bp = (unsigned short*)(ws + 25165824);
    float* dwT = (float*)ws;                      // reuses A'/B' post-GEMM

    prep_split<<<Bm_, 256, 0, stream>>>(x, Ap, 1024, 2048);
    prep_split<<<Hh_, 256, 0, stream>>>(enc, Bp, 2048, 1024);
    gemm_acts<<<(Bm_ / GBM) * (Hh_ / GBN), 512, 0, stream>>>(Ap, Bp, latent);
    transpose_dw<<<dim3(Hh_ / 32, Dd_ / 32), 256, 0, stream>>>(dw, dwT);
    topk_refine_recon<<<Bm_, 256, 0, stream>>>(latent, x, enc, dwT, db, recon);
}